// Round 17
// baseline (450.109 us; speedup 1.0000x reference)
//
#include <hip/hip_runtime.h>
#include <hip/hip_bf16.h>

typedef __attribute__((ext_vector_type(8))) short bf16x8;
typedef __attribute__((ext_vector_type(4))) float f32x4;

#define B_SZ   1024
#define T_SZ   128
#define L_SZ   256
#define F_SZ   784
#define M_TOT  (B_SZ * T_SZ)            // 131072
#define BK     32
#define KSTEPS 25                       // ceil(784/32), tail zero-padded
#define KCHUNKS 100                     // 25*4 chunks of 8 k-values

#define WPRE_ELEMS (KSTEPS * 4 * L_SZ)  // 25600 bf16x8 elements
#define WPRE_BYTES (WPRE_ELEMS * 16)    // 409600
#define CDIFF_ELEMS (T_SZ * L_SZ)       // 32768
#define WS_NEED (WPRE_BYTES + CDIFF_ELEMS * 4)

// v15 LDS map: buf0 [0,51200) | buf1 [51200,102400) | 8 slabs x 2176B
#define BUFB     51200
#define SLAB_OFF 102400
#define SLABB    2176                   // 16 rows x 34 floats x 4B
#define SMEM_SZ  119808                 // 117 KB (<= 128KB proven on gfx950)

__device__ __forceinline__ unsigned short f2bf(float f) {
    __hip_bfloat16 h = __float2bfloat16(f);   // RTNE
    return *reinterpret_cast<unsigned short*>(&h);
}

// ---------------- prep: W -> bf16 MFMA-fragment layout; cdiff = c0 - c1 ----
// wpre[ks][kgrp][leaf] : bf16x8 = W[leaf][ks*32+kgrp*8 .. +8), 0-padded tail
__global__ __launch_bounds__(256) void dn_prep(
    const float* __restrict__ W, const float* __restrict__ contrib,
    unsigned short* __restrict__ wpre, float* __restrict__ cdiff)
{
    const int gid = blockIdx.x * 256 + threadIdx.x;
    if (gid < WPRE_ELEMS) {
        const int leaf = gid & 255;
        const int kg   = (gid >> 8) & 3;
        const int ks   = gid >> 10;
        const int k0   = ks * BK + kg * 8;
        bf16x8 v;
        #pragma unroll
        for (int j = 0; j < 8; ++j) {
            const int k = k0 + j;
            const float f = (k < F_SZ) ? W[(size_t)leaf * F_SZ + k] : 0.f;
            v[j] = (short)f2bf(f);
        }
        *reinterpret_cast<bf16x8*>(wpre + (size_t)gid * 8) = v;
    } else {
        const int cid = gid - WPRE_ELEMS;
        if (cid < CDIFF_ELEMS)
            cdiff[cid] = contrib[(size_t)cid * 2] - contrib[(size_t)cid * 2 + 1];
    }
}

// ---------------- v15: producer/consumer wave specialization ---------------
// Grid 1024, 1024 thr (16 waves), 1 block/CU. Block owns 128 rows = 4 strips
// of 32. Waves 0-7 PRODUCE: stage strip s+1 (contiguous 1KB global chunks,
// f32->bf16 cvt, v8's XOR-swizzled LDS layout) into buf[(s+1)&1]. Waves 8-15
// CONSUME: v7-proven K-loop (wave tile 32x32, 1-deep W L2 prefetch) on
// buf[s&1], then epilogue via WAVE-PRIVATE half-slab transpose (no cross-wave
// sync inside divergent code) with full-line 128B stores. ONE __syncthreads
// per strip, always at top level. Overlap comes from the CU scheduler running
// producer waves (HBM-latency-bound) concurrently with consumer waves
// (MFMA/L2-bound) — nothing for the compiler to sink or drain (m114).
__global__ __launch_bounds__(1024, 4) void dn_fused15(
    const float* __restrict__ x, const unsigned short* __restrict__ wpre,
    const float* __restrict__ bias, const float* __restrict__ cdiff,
    float* __restrict__ out)
{
    __shared__ __align__(16) unsigned char smem[SMEM_SZ];

    const int tid    = threadIdx.x;
    const int lane   = tid & 63;
    const int wid    = tid >> 6;        // 0..15
    const int rowBlk = blockIdx.x * 128;
    const size_t GOFF = (size_t)M_TOT * L_SZ;

    // ---- producer: stage strip st into buf[st&1] (3200 chunks / 512 lanes)
    auto STAGE = [&](int st) {
        bf16x8* As = reinterpret_cast<bf16x8*>(smem + (size_t)(st & 1) * BUFB);
        const size_t rb = (size_t)(rowBlk + st * 32);
        for (int i = wid * 64 + lane; i < 32 * KCHUNKS; i += 512) {
            const int row = i / KCHUNKS;
            const int kc  = i - row * KCHUNKS;
            bf16x8 v;
            if (kc < 98) {
                const float* p = x + (rb + row) * F_SZ + kc * 8;
                const f32x4 lo = *reinterpret_cast<const f32x4*>(p);
                const f32x4 hi = *reinterpret_cast<const f32x4*>(p + 4);
                #pragma unroll
                for (int j = 0; j < 4; ++j) {
                    v[j]     = (short)f2bf(lo[j]);
                    v[4 + j] = (short)f2bf(hi[j]);
                }
            } else {
                #pragma unroll
                for (int j = 0; j < 8; ++j) v[j] = 0;
            }
            As[kc * 32 + (row ^ (kc & 7))] = v;
        }
    };

    // ---- consumer constants ----
    const int cw      = wid - 8;        // 0..7 (consumers only)
    const int colBase = cw * 32;
    const int lr      = lane & 15;
    const int kseg    = lane >> 4;
    const unsigned short* wpb =
        wpre + ((size_t)kseg * L_SZ + colBase + lr) * 8;
    float* slab = reinterpret_cast<float*>(smem + SLAB_OFF + cw * SLABB);
    const int erow8 = lane >> 3;        // 0..7
    const int ecol  = (lane & 7) * 4;   // 0..28

    // prologue: stage strip 0
    if (wid < 8) STAGE(0);
    __syncthreads();

    for (int st = 0; st < 4; ++st) {
        if (wid < 8) {
            if (st < 3) STAGE(st + 1);   // flies under consumers' compute
        } else {
            // ---- K-loop on buf[st&1] ----
            const unsigned char* Ab = smem + (size_t)(st & 1) * BUFB;
            f32x4 acc[2][2];
            #pragma unroll
            for (int mi = 0; mi < 2; ++mi)
                #pragma unroll
                for (int ni = 0; ni < 2; ++ni)
                    acc[mi][ni] = (f32x4){0.f, 0.f, 0.f, 0.f};

            bf16x8 wcur[2], wnxt[2];
            wcur[0] = *reinterpret_cast<const bf16x8*>(wpb);
            wcur[1] = *reinterpret_cast<const bf16x8*>(wpb + 128);

            #pragma unroll
            for (int ks = 0; ks < KSTEPS; ++ks) {
                if (ks + 1 < KSTEPS) {
                    wnxt[0] = *reinterpret_cast<const bf16x8*>(wpb + (size_t)(ks + 1) * 8192);
                    wnxt[1] = *reinterpret_cast<const bf16x8*>(wpb + (size_t)(ks + 1) * 8192 + 128);
                }
                const int kcr = ks * 4 + kseg;
                const bf16x8 a0 = *reinterpret_cast<const bf16x8*>(
                    Ab + (size_t)(kcr * 32 + (lr ^ (kcr & 7))) * 16);
                const bf16x8 a1 = *reinterpret_cast<const bf16x8*>(
                    Ab + (size_t)(kcr * 32 + ((16 + lr) ^ (kcr & 7))) * 16);

                acc[0][0] = __builtin_amdgcn_mfma_f32_16x16x32_bf16(a0, wcur[0], acc[0][0], 0, 0, 0);
                acc[0][1] = __builtin_amdgcn_mfma_f32_16x16x32_bf16(a0, wcur[1], acc[0][1], 0, 0, 0);
                acc[1][0] = __builtin_amdgcn_mfma_f32_16x16x32_bf16(a1, wcur[0], acc[1][0], 0, 0, 0);
                acc[1][1] = __builtin_amdgcn_mfma_f32_16x16x32_bf16(a1, wcur[1], acc[1][1], 0, 0, 0);
                wcur[0] = wnxt[0];
                wcur[1] = wnxt[1];
            }

            // ---- epilogue: wave-private half-slab transpose ----
            float spv[2][2][4];
            #pragma unroll
            for (int ni = 0; ni < 2; ++ni) {
                const float bb = bias[colBase + ni * 16 + lr];
                #pragma unroll
                for (int mi = 0; mi < 2; ++mi)
                    #pragma unroll
                    for (int r = 0; r < 4; ++r)
                        spv[mi][ni][r] = fminf(fmaxf(acc[mi][ni][r] + bb, -1.f), 1.f);
            }
            const int rowB = rowBlk + st * 32;

            // pass 1: sp (two 16-row halves)
            #pragma unroll
            for (int h = 0; h < 2; ++h) {
                #pragma unroll
                for (int ni = 0; ni < 2; ++ni)
                    #pragma unroll
                    for (int r = 0; r < 4; ++r)
                        slab[(kseg * 4 + r) * 34 + ni * 16 + lr] = spv[h][ni][r];
                #pragma unroll
                for (int j = 0; j < 2; ++j) {
                    const int row = j * 8 + erow8;
                    const f32x4 v = *reinterpret_cast<const f32x4*>(slab + row * 34 + ecol);
                    *reinterpret_cast<f32x4*>(out + (size_t)(rowB + h * 16 + row) * L_SZ
                                              + colBase + ecol) = v;
                }
            }
            // pass 2: gini (two 16-row halves)
            #pragma unroll
            for (int h = 0; h < 2; ++h) {
                #pragma unroll
                for (int ni = 0; ni < 2; ++ni) {
                    const int col = colBase + ni * 16 + lr;
                    #pragma unroll
                    for (int r = 0; r < 4; ++r) {
                        const int t = (rowB + h * 16 + kseg * 4 + r) & (T_SZ - 1);
                        const float d  = spv[h][ni][r] * cdiff[t * L_SZ + col];
                        const float ed = __expf(d);
                        const float s2 = ed / (1.f + ed);
                        slab[(kseg * 4 + r) * 34 + col - colBase] = fmaf(2.f * s2, 1.f - s2, 1.f);
                    }
                }
                #pragma unroll
                for (int j = 0; j < 2; ++j) {
                    const int row = j * 8 + erow8;
                    const f32x4 v = *reinterpret_cast<const f32x4*>(slab + row * 34 + ecol);
                    *reinterpret_cast<f32x4*>(out + GOFF + (size_t)(rowB + h * 16 + row) * L_SZ
                                              + colBase + ecol) = v;
                }
            }
        }
        __syncthreads();   // strip boundary: buf swap safe, all at top level
    }
}

// ---------------- v1 fallback (no workspace needed) ------------------------
__global__ __launch_bounds__(512) void dn_fused_v1(
    const float* __restrict__ x, const float* __restrict__ W,
    const float* __restrict__ bias, const float* __restrict__ contrib,
    float* __restrict__ out)
{
    __shared__ bf16x8 As[4][128];
    __shared__ bf16x8 Bs[4][L_SZ];

    const int tid    = threadIdx.x;
    const int lane   = tid & 63;
    const int wid    = tid >> 6;
    const int waveM  = wid >> 2;
    const int waveN  = wid & 3;
    const int blkRow = blockIdx.x * 128;
    const int ar = tid >> 2;
    const int ak = (tid & 3) * 8;
    const int wr = tid >> 1;
    const int wk = (tid & 1) * 16;
    const int laneRow = lane & 15;
    const int kgrp    = lane >> 4;

    f32x4 acc[4][4];
    #pragma unroll
    for (int i = 0; i < 4; ++i)
        #pragma unroll
        for (int j = 0; j < 4; ++j)
            acc[i][j] = (f32x4){0.f, 0.f, 0.f, 0.f};

    const float* xrow = x + (size_t)(blkRow + ar) * F_SZ;
    const float* wrow = W + (size_t)wr * F_SZ;
    const f32x4 zf = {0.f, 0.f, 0.f, 0.f};

    f32x4 xa0 = *reinterpret_cast<const f32x4*>(xrow + ak);
    f32x4 xa1 = *reinterpret_cast<const f32x4*>(xrow + ak + 4);
    f32x4 wa0 = *reinterpret_cast<const f32x4*>(wrow + wk);
    f32x4 wa1 = *reinterpret_cast<const f32x4*>(wrow + wk + 4);
    f32x4 wa2 = *reinterpret_cast<const f32x4*>(wrow + wk + 8);
    f32x4 wa3 = *reinterpret_cast<const f32x4*>(wrow + wk + 12);

    for (int ks = 0; ks < KSTEPS; ++ks) {
        bf16x8 av, wv0, wv1;
        #pragma unroll
        for (int j = 0; j < 4; ++j) {
            av[j]      = (short)f2bf(xa0[j]);
            av[4 + j]  = (short)f2bf(xa1[j]);
            wv0[j]     = (short)f2bf(wa0[j]);
            wv0[4 + j] = (short)f2bf(wa1[j]);
            wv1[j]     = (short)f2bf(wa2[j]);
            wv1[4 + j] = (short)f2bf(wa3[j]);
        }
        As[ak >> 3][ar] = av;
        Bs[wk >> 3][wr] = wv0;
        Bs[(wk >> 3) + 1][wr] = wv1;
        __syncthreads();

        if (ks + 1 < KSTEPS) {
            const int kb = (ks + 1) * BK;
            if (kb + ak < F_SZ) {
                xa0 = *reinterpret_cast<const f32x4*>(xrow + kb + ak);
                xa1 = *reinterpret_cast<const f32x4*>(xrow + kb + ak + 4);
            } else { xa0 = zf; xa1 = zf; }
            if (kb + wk < F_SZ) {
                wa0 = *reinterpret_cast<const f32x4*>(wrow + kb + wk);
                wa1 = *reinterpret_cast<const f32x4*>(wrow + kb + wk + 4);
                wa2 = *reinterpret_cast<const f32x4*>(wrow + kb + wk + 8);
                wa3 = *reinterpret_cast<const f32x4*>(wrow + kb + wk + 12);
            } else { wa0 = zf; wa1 = zf; wa2 = zf; wa3 = zf; }
        }

        bf16x8 af[4], bfv[4];
        #pragma unroll
        for (int mi = 0; mi < 4; ++mi)
            af[mi] = As[kgrp][waveM * 64 + mi * 16 + laneRow];
        #pragma unroll
        for (int ni = 0; ni < 4; ++ni)
            bfv[ni] = Bs[kgrp][waveN * 64 + ni * 16 + laneRow];
        #pragma unroll
        for (int mi = 0; mi < 4; ++mi)
            #pragma unroll
            for (int ni = 0; ni < 4; ++ni)
                acc[mi][ni] = __builtin_amdgcn_mfma_f32_16x16x32_bf16(
                    af[mi], bfv[ni], acc[mi][ni], 0, 0, 0);
        __syncthreads();
    }

    const size_t GOFF  = (size_t)M_TOT * L_SZ;
    const int    rbase = waveM * 64 + (lane >> 4) * 4;
    const int    cbase = waveN * 64 + laneRow;
    #pragma unroll
    for (int ni = 0; ni < 4; ++ni) {
        const int col = cbase + ni * 16;
        const float bb = bias[col];
        #pragma unroll
        for (int mi = 0; mi < 4; ++mi) {
            #pragma unroll
            for (int r = 0; r < 4; ++r) {
                const int m = blkRow + rbase + mi * 16 + r;
                const int t = m & (T_SZ - 1);
                float v  = acc[mi][ni][r] + bb;
                float sp = fminf(fmaxf(v, -1.f), 1.f);
                const float* cp = contrib + (size_t)(t * L_SZ + col) * 2;
                const float d  = sp * (cp[0] - cp[1]);
                const float ed = __expf(d);
                const float s  = ed / (1.f + ed);
                const float g  = fmaf(2.f * s, 1.f - s, 1.f);
                const size_t o = (size_t)m * L_SZ + col;
                out[o]        = sp;
                out[GOFF + o] = g;
            }
        }
    }
}

extern "C" void kernel_launch(void* const* d_in, const int* in_sizes, int n_in,
                              void* d_out, int out_size, void* d_ws, size_t ws_size,
                              hipStream_t stream) {
    const float* x       = (const float*)d_in[0];
    const float* W       = (const float*)d_in[1];
    const float* bias    = (const float*)d_in[2];
    const float* contrib = (const float*)d_in[3];
    float* out = (float*)d_out;

    if (ws_size >= (size_t)WS_NEED && d_ws != nullptr) {
        unsigned short* wpre  = (unsigned short*)d_ws;
        float*          cdiff = (float*)((char*)d_ws + WPRE_BYTES);
        const int prep_threads = WPRE_ELEMS + CDIFF_ELEMS;
        dn_prep<<<(prep_threads + 255) / 256, 256, 0, stream>>>(W, contrib, wpre, cdiff);
        dn_fused15<<<M_TOT / 128, 1024, 0, stream>>>(x, wpre, bias, cdiff, out);
    } else {
        dn_fused_v1<<<M_TOT / 128, 512, 0, stream>>>(x, W, bias, contrib, out);
    }
}